// Round 4
// baseline (1222.909 us; speedup 1.0000x reference)
//
#include <hip/hip_runtime.h>

// Problem constants
constexpr int CIN   = 256;   // feature channels
constexpr int KD    = 32;    // key dim
constexpr int VD    = 128;   // value dim
constexpr int NCLS  = 10;
constexpr int BS    = 4;
constexpr int HW    = 256;   // 16*16
constexpr int NJOBS = 30;    // 5 levels * 4 images + 10 template images
constexpr float BNC = 0.9999950000374997f; // 1/sqrt(1+1e-5)

static __device__ __forceinline__ int imin(int a, int b) { return a < b ? a : b; }

// ---------------------------------------------------------------------------
// Weight-amortized conv3x3 partial. Block = (group g, ocg of 8, ks split);
// processes NIMG images sharing one weight set.
//  - WSHARED=false: weights w + g*OC*CIN*9 (per-level), images in + (g*NIMG+img)
//  - WSHARED=true : single weight set, images in + (g*NIMG+img)
// part[(ks*NJOBS + job_base + g*NIMG + img)*OC + oc][px], partial over
// channels [ks*CPB, +CPB).
template<int KS_, int NIMG, bool WSHARED>
__global__ __launch_bounds__(256) void k_conv_part(
    const float* __restrict__ in, const float* __restrict__ w,
    float* __restrict__ part, int OC, int job_base) {
  constexpr int CPB = 256 / KS_;
  int nt  = OC >> 3;
  int g   = blockIdx.x / (nt * KS_);
  int rem = blockIdx.x % (nt * KS_);
  int ks  = rem / nt, ocg = rem % nt;
  int tid = threadIdx.x;
  int y = tid >> 4, x = tid & 15;

  __shared__ float sm[NIMG][4][18][18];
  for (int i = tid; i < NIMG * 4 * 324; i += 256) ((float*)sm)[i] = 0.f;

  float acc[NIMG][8];
#pragma unroll
  for (int im = 0; im < NIMG; ++im)
#pragma unroll
    for (int o = 0; o < 8; ++o) acc[im][o] = 0.f;

  const float* inb = in + ((size_t)(g * NIMG) * CIN + ks * CPB) * HW;
  const float* wb  = (WSHARED ? w : w + (size_t)g * OC * CIN * 9)
                     + ((size_t)(ocg * 8) * CIN + ks * CPB) * 9;

  for (int ch = 0; ch < CPB / 4; ++ch) {
    __syncthreads();   // covers zero-fill first iter, compute later iters
#pragma unroll
    for (int im = 0; im < NIMG; ++im)
#pragma unroll
      for (int pch = 0; pch < 4; ++pch)
        sm[im][pch][y + 1][x + 1] = inb[((size_t)im * CIN + ch * 4 + pch) * HW + tid];
    __syncthreads();
#pragma unroll
    for (int pch = 0; pch < 4; ++pch) {
      float r[NIMG][9];
#pragma unroll
      for (int im = 0; im < NIMG; ++im) {
        r[im][0] = sm[im][pch][y][x];     r[im][1] = sm[im][pch][y][x + 1];     r[im][2] = sm[im][pch][y][x + 2];
        r[im][3] = sm[im][pch][y + 1][x]; r[im][4] = sm[im][pch][y + 1][x + 1]; r[im][5] = sm[im][pch][y + 1][x + 2];
        r[im][6] = sm[im][pch][y + 2][x]; r[im][7] = sm[im][pch][y + 2][x + 1]; r[im][8] = sm[im][pch][y + 2][x + 2];
      }
      int c = ch * 4 + pch;
#pragma unroll
      for (int o = 0; o < 8; ++o) {
        const float* wp = wb + ((size_t)o * CIN + c) * 9;   // wave-uniform -> s_load
        float w0 = wp[0], w1 = wp[1], w2 = wp[2], w3 = wp[3], w4 = wp[4],
              w5 = wp[5], w6 = wp[6], w7 = wp[7], w8 = wp[8];
#pragma unroll
        for (int im = 0; im < NIMG; ++im)
          acc[im][o] += w0 * r[im][0] + w1 * r[im][1] + w2 * r[im][2]
                      + w3 * r[im][3] + w4 * r[im][4] + w5 * r[im][5]
                      + w6 * r[im][6] + w7 * r[im][7] + w8 * r[im][8];
      }
    }
  }
#pragma unroll
  for (int im = 0; im < NIMG; ++im)
    for (int o = 0; o < 8; ++o)
      part[(((size_t)ks * NJOBS + job_base + g * NIMG + im) * OC + ocg * 8 + o) * HW + tid]
          = acc[im][o];
}

// reduce over KS partials, add bias, scale. total = NJOBS*OC*HW.
// jobs<20 -> out_lvl[(job*outC_lvl + oc)*HW + px], bias per level, *scale_lvl
// jobs>=20 -> out_tmpl[((job-20)*OC + oc)*HW + px], bias_tmpl, *1
template<int KS_>
__global__ __launch_bounds__(256) void k_conv_red(
    const float* __restrict__ part,
    const float* __restrict__ bias_lvl, const float* __restrict__ bias_tmpl,
    float* __restrict__ out_lvl, float* __restrict__ out_tmpl,
    int OC, int outC_lvl, float scale_lvl) {
  int idx = blockIdx.x * 256 + threadIdx.x;
  int px  = idx & 255;
  int oc  = (idx >> 8) % OC;
  int job = idx / (OC * HW);
  size_t stride = (size_t)NJOBS * OC * HW;
  const float* pp = part + idx;
  float s = 0.f;
#pragma unroll
  for (int k = 0; k < KS_; ++k) s += pp[k * stride];
  if (job < 20)
    out_lvl[((size_t)job * outC_lvl + oc) * HW + px] =
        (s + bias_lvl[(job >> 2) * OC + oc]) * scale_lvl;
  else
    out_tmpl[((size_t)(job - 20) * OC + oc) * HW + px] = s + bias_tmpl[oc];
}

// ---------------------------------------------------------------------------
// resize all 5 levels' features to 16x16: fr_all[l*4+b][c][256].
// grid = 5*4*256 planes, block = 256 px.
__global__ __launch_bounds__(256) void k_resize_all(
    const float* __restrict__ f0, const float* __restrict__ f1,
    const float* __restrict__ f2, const float* __restrict__ f3,
    const float* __restrict__ f4, float* __restrict__ fr_all) {
  int plane = blockIdx.x, px = threadIdx.x;
  int l = plane >> 10, pb = plane & 1023;
  int S = 64 >> l;
  const float* fin;
  switch (l) {
    case 0: fin = f0; break; case 1: fin = f1; break; case 2: fin = f2; break;
    case 3: fin = f3; break; default: fin = f4; break;
  }
  fin += (size_t)pb * S * S;
  int Y = px >> 4, X = px & 15;
  float cyf = (float)(Y * (S - 1)) / 15.0f;
  int ylo = imin((int)cyf, S - 2); float fy = cyf - (float)ylo;
  float cxf = (float)(X * (S - 1)) / 15.0f;
  int xlo = imin((int)cxf, S - 2); float fx = cxf - (float)xlo;
  float v0 = fin[ylo * S + xlo],       v1 = fin[ylo * S + xlo + 1];
  float v2 = fin[(ylo + 1) * S + xlo], v3 = fin[(ylo + 1) * S + xlo + 1];
  fr_all[(size_t)plane * HW + px] =
      (1.f - fy) * ((1.f - fx) * v0 + fx * v1) + fy * ((1.f - fx) * v2 + fx * v3);
}

// ---------------------------------------------------------------------------
// Fused p: scores + softmax(over i) + normalized write, one level.
// grid = 40*4 (bn, jt); block = 256 = 4 iq-waves x 64 j.
// p[bn][i][j] = exp(score - m_j) / s_j
__global__ __launch_bounds__(256) void k_p_fused(
    const float* __restrict__ kq_lvl, const float* __restrict__ ktb,
    float* __restrict__ p) {
  int bn = blockIdx.x >> 2, jt = blockIdx.x & 3;
  int b = bn / NCLS, n = bn % NCLS;
  int t = threadIdx.x;
  int iq = t >> 6, jl = t & 63;
  int j = jt * 64 + jl;

  __shared__ float kqs[KD][HW];   // 32 KB; reused for stats after compute
  float ktr[KD];
#pragma unroll
  for (int k = 0; k < KD; ++k) ktr[k] = ktb[((size_t)n * KD + k) * HW + j];
  const float* kqb = kq_lvl + (size_t)b * KD * HW;
  for (int s = t; s < KD * HW; s += 256) ((float*)kqs)[s] = kqb[s];
  __syncthreads();

  float v[64];
#pragma unroll
  for (int ii = 0; ii < 64; ++ii) v[ii] = 0.f;
  for (int k = 0; k < KD; ++k) {
    float a = ktr[k];
    const float4* q4 = (const float4*)&kqs[k][iq * 64];
#pragma unroll
    for (int q = 0; q < 16; ++q) {
      float4 u = q4[q];
      v[q * 4 + 0] += u.x * a; v[q * 4 + 1] += u.y * a;
      v[q * 4 + 2] += u.z * a; v[q * 4 + 3] += u.w * a;
    }
  }
  // per-thread partial stats over its 64 i's
  float ml = -1e30f;
#pragma unroll
  for (int ii = 0; ii < 64; ++ii) ml = fmaxf(ml, v[ii]);
  float sl = 0.f;
#pragma unroll
  for (int ii = 0; ii < 64; ++ii) sl += __expf(v[ii] - ml);

  __syncthreads();                 // all waves done reading kqs
  float* red = (float*)kqs;        // [0..255]=m, [256..511]=s
  red[iq * 64 + jl] = ml;
  red[256 + iq * 64 + jl] = sl;
  __syncthreads();
  float M = -1e30f;
#pragma unroll
  for (int q = 0; q < 4; ++q) M = fmaxf(M, red[q * 64 + jl]);
  float S = 0.f;
#pragma unroll
  for (int q = 0; q < 4; ++q) S += red[256 + q * 64 + jl] * __expf(red[q * 64 + jl] - M);
  float inv = 1.0f / S;

  float* pb = p + (size_t)bn * HW * HW + j;
#pragma unroll
  for (int ii = 0; ii < 64; ++ii)
    pb[(size_t)(iq * 64 + ii) * HW] = __expf(v[ii] - M) * inv;
}

// ---------------------------------------------------------------------------
// fa via LDS transpose: block = (bn, jg of 16 j's). Stage p[:,16j] tile,
// emit 16*S*S pixels with coalesced float4 stores.
__global__ __launch_bounds__(256) void k_fa_t(
    const float* __restrict__ p, float* __restrict__ out, int S, int shift) {
  int bn = blockIdx.x >> 4, jg = blockIdx.x & 15;
  int tid = threadIdx.x;
  __shared__ float ld[256][17];
  const float* pb = p + (size_t)bn * HW * HW + jg * 16;
  for (int t = tid; t < 4096; t += 256)
    ld[t >> 4][t & 15] = pb[(size_t)(t >> 4) * HW + (t & 15)];
  __syncthreads();

  int SS = S * S, tot = SS << 4;
  for (int base = tid * 4; base < tot; base += 1024) {
    int jj = base >> (2 * shift);
    int rest = base & (SS - 1);
    int X0 = rest & (S - 1), Y = rest >> shift;
    float cyf = (float)(Y * 15) / (float)(S - 1);
    int ylo = imin((int)cyf, 14); float fy = cyf - (float)ylo;
    float4 r; float* rr = (float*)&r;
#pragma unroll
    for (int t4 = 0; t4 < 4; ++t4) {
      int X = X0 + t4;
      float cxf = (float)(X * 15) / (float)(S - 1);
      int xlo = imin((int)cxf, 14); float fx = cxf - (float)xlo;
      int i00 = ylo * 16 + xlo;
      float v0 = ld[i00][jj],      v1 = ld[i00 + 1][jj];
      float v2 = ld[i00 + 16][jj], v3 = ld[i00 + 17][jj];
      rr[t4] = (1.f - fy) * ((1.f - fx) * v0 + fx * v1)
             + fy * ((1.f - fx) * v2 + fx * v3);
    }
    *(float4*)(out + ((size_t)bn * HW + jg * 16 + jj) * SS + rest) = r;
  }
}

// ---------------------------------------------------------------------------
// aggn[bn,c,j] = sum_i vt[n,c,i] * p[bn,i,j]. grid = 40*8 (ctile 16)
__global__ __launch_bounds__(256) void k_aggn(
    const float* __restrict__ vt, const float* __restrict__ p, float* __restrict__ aggn) {
  int blk = blockIdx.x;
  int ct = blk & 7, bn = blk >> 3;
  int n = bn % NCLS;
  int j = threadIdx.x;
  __shared__ float vts[16][HW];
  for (int c = 0; c < 16; ++c) vts[c][j] = vt[((size_t)n * VD + ct * 16 + c) * HW + j];
  __syncthreads();
  float acc[16] = {};
  const float* pp = p + (size_t)bn * HW * HW + j;
  for (int i = 0; i < HW; ++i) {
    float pv = pp[(size_t)i * HW];
#pragma unroll
    for (int c = 0; c < 16; ++c) acc[c] += vts[c][i] * pv;
  }
  for (int c = 0; c < 16; ++c)
    aggn[((size_t)bn * VD + ct * 16 + c) * HW + j] = acc[c];
}

// f16[b, 128+c, j] = sum_n aggn[b,n,c,j].  total = BS*VD*HW = 131072
__global__ __launch_bounds__(256) void k_aggred(
    const float* __restrict__ aggn, float* __restrict__ f16) {
  int idx = blockIdx.x * 256 + threadIdx.x;
  int j = idx & 255;
  int c = (idx >> 8) & 127;
  int b = idx >> 15;
  float s = 0.f;
#pragma unroll
  for (int n = 0; n < NCLS; ++n)
    s += aggn[(((size_t)b * NCLS + n) * VD + c) * HW + j];
  f16[((size_t)b * CIN + VD + c) * HW + j] = s;
}

// ---------------------------------------------------------------------------
// g16_all[l,b,oc,j] = sum_c cw[oc,256+c]*(gamma[l,c]*BNC)*f16_all[l,b,c,j]
// grid = 5*4*32 (8 oc per block)
__global__ __launch_bounds__(256) void k_g16_all(
    const float* __restrict__ f16_all, const float* __restrict__ cw,
    const float* __restrict__ gamma, float* __restrict__ g16_all) {
  int blk = blockIdx.x;
  int l = blk >> 7, b = (blk >> 5) & 3, ocg = blk & 31;
  int j = threadIdx.x;
  const float* f16 = f16_all + (size_t)(l * 4 + b) * CIN * HW;
  const float* gm  = gamma + l * CIN;
  float acc[8] = {};
  for (int c = 0; c < CIN; ++c) {
    float fv = f16[(size_t)c * HW + j] * (gm[c] * BNC);
#pragma unroll
    for (int o = 0; o < 8; ++o)
      acc[o] += cw[(size_t)(ocg * 8 + o) * 512 + 256 + c] * fv;
  }
  for (int o = 0; o < 8; ++o)
    g16_all[((size_t)(l * 4 + b) * CIN + ocg * 8 + o) * HW + j] = acc[o];
}

// cb[l,oc] = combine_b[oc] + sum_c cw[oc,256+c]*beta[l,c].  grid=5, block=256
__global__ __launch_bounds__(256) void k_cb(
    const float* __restrict__ cw, const float* __restrict__ cbias,
    const float* __restrict__ beta, float* __restrict__ cb) {
  int l = blockIdx.x, oc = threadIdx.x;
  float s = cbias[oc];
  for (int c = 0; c < CIN; ++c)
    s += cw[(size_t)oc * 512 + 256 + c] * beta[l * CIN + c];
  cb[l * CIN + oc] = s;
}

// ---------------------------------------------------------------------------
// out[b,oc,Y,X] = sum_c cw[oc,c]*f[b,c,Y,X] + bilinear(g16[b,oc])(Y,X) + cb[oc]
// 32 oc per block; grid = BS*8*chunks
__global__ __launch_bounds__(256) void k_out(
    const float* __restrict__ f, const float* __restrict__ cw,
    const float* __restrict__ g16, const float* __restrict__ cb,
    float* __restrict__ out, int S, int shift, int chunks) {
  int blk = blockIdx.x;
  int ch = blk % chunks;
  int t = blk / chunks;
  int ocg = t & 7, b = t >> 3;
  int pix = ch * 256 + threadIdx.x;
  int SS = S * S;
  if (pix >= SS) return;
  int X = pix & (S - 1), Y = pix >> shift;
  float acc[32] = {};
  const float* fb = f + (size_t)b * CIN * SS + pix;
  for (int c = 0; c < CIN; ++c) {
    float fv = fb[(size_t)c * SS];
#pragma unroll
    for (int o = 0; o < 32; ++o)
      acc[o] += cw[(size_t)(ocg * 32 + o) * 512 + c] * fv;
  }
  float cyf = (float)(Y * 15) / (float)(S - 1);
  int ylo = imin((int)cyf, 14); float fy = cyf - (float)ylo;
  float cxf = (float)(X * 15) / (float)(S - 1);
  int xlo = imin((int)cxf, 14); float fx = cxf - (float)xlo;
  const float* gb = g16 + ((size_t)b * CIN + ocg * 32) * HW + ylo * 16 + xlo;
#pragma unroll
  for (int o = 0; o < 32; ++o) {
    const float* g = gb + (size_t)o * HW;
    float v0 = g[0], v1 = g[1], v2 = g[16], v3 = g[17];
    float bil = (1.f - fy) * ((1.f - fx) * v0 + fx * v1)
              + fy * ((1.f - fx) * v2 + fx * v3);
    out[((size_t)b * CIN + ocg * 32 + o) * SS + pix] = acc[o] + bil + cb[ocg * 32 + o];
  }
}

// ===========================================================================
extern "C" void kernel_launch(void* const* d_in, const int* in_sizes, int n_in,
                              void* d_out, int out_size, void* d_ws, size_t ws_size,
                              hipStream_t stream) {
  const float* feat[5];
  for (int l = 0; l < 5; ++l) feat[l] = (const float*)d_in[l];
  const float* att   = (const float*)d_in[5];
  const float* ktw   = (const float*)d_in[6];
  const float* ktb   = (const float*)d_in[7];
  const float* vtw   = (const float*)d_in[8];
  const float* vtb   = (const float*)d_in[9];
  const float* kqw   = (const float*)d_in[10];
  const float* kqb   = (const float*)d_in[11];
  const float* vqw   = (const float*)d_in[12];
  const float* vqb   = (const float*)d_in[13];
  const float* gamma = (const float*)d_in[14];
  const float* beta  = (const float*)d_in[15];
  const float* cw    = (const float*)d_in[16];
  const float* cbias = (const float*)d_in[17];
  float* out = (float*)d_out;

  // workspace layout (floats), total ~8.44M fl = 33.8 MB
  float* ws      = (float*)d_ws;
  float* kqall   = ws;                    // [30][32][256]      = 245760
  float* vt      = kqall  + 245760;       // [10][128][256]     = 327680
  float* fr_all  = vt     + 327680;       // [20][256][256]     = 1310720
  float* f16_all = fr_all + 1310720;      // [20][256][256]     = 1310720
  float* g16_all = f16_all+ 1310720;      // [20][256][256]     = 1310720
  float* cb      = g16_all+ 1310720;      // [5][256]           = 1280
  float* p       = cb     + 1280;         // [40][256][256]     = 2621440
  float* aggn    = p      + 2621440;      // [40][128][256]     = 1310720
  float* part    = p;                     // conv partials alias p+aggn (3932160 fl)

  static const int sizes[5]  = {64, 32, 16, 8, 4};
  static const int shifts[5] = {6, 5, 4, 3, 2};
  size_t out_off[5], fa_off[5];
  {
    size_t off = 0;
    for (int l = 0; l < 5; ++l) { out_off[l] = off; off += (size_t)BS * CIN * sizes[l] * sizes[l]; }
    for (int l = 0; l < 5; ++l) { fa_off[l] = off; off += (size_t)BS * NCLS * HW * sizes[l] * sizes[l]; }
  }

  // Stage 1: resize + all convs (weight-amortized, batched)
  k_resize_all<<<5 * 4 * 256, 256, 0, stream>>>(
      feat[0], feat[1], feat[2], feat[3], feat[4], fr_all);
  // K convs: KS=16 (CPB=16). part = 16*30*32*256 = 3.93M floats.
  k_conv_part<16, 4, false><<<5 * (KD / 8) * 16, 256, 0, stream>>>(
      fr_all, kqw, part, KD, 0);
  k_conv_part<16, 5, true><<<2 * (KD / 8) * 16, 256, 0, stream>>>(
      att, ktw, part, KD, 20);
  k_conv_red<16><<<NJOBS * KD * HW / 256, 256, 0, stream>>>(
      part, kqb, ktb, kqall, kqall + 20 * KD * HW, KD, KD, 1.f);
  // V convs: KS=4 (CPB=64). part = 4*30*128*256 = 3.93M floats.
  k_conv_part<4, 4, false><<<5 * (VD / 8) * 4, 256, 0, stream>>>(
      fr_all, vqw, part, VD, 0);
  k_conv_part<4, 5, true><<<2 * (VD / 8) * 4, 256, 0, stream>>>(
      att, vtw, part, VD, 20);
  k_conv_red<4><<<NJOBS * VD * HW / 256, 256, 0, stream>>>(
      part, vqb, vtb, f16_all, vt, VD, CIN, (float)NCLS);
  k_cb<<<5, 256, 0, stream>>>(cw, cbias, beta, cb);

  // Stage 2: per-level p-chain (p buffer reused)
  for (int l = 0; l < 5; ++l) {
    k_p_fused<<<40 * 4, 256, 0, stream>>>(
        kqall + (size_t)l * 4 * KD * HW, kqall + 20 * KD * HW, p);
    k_fa_t<<<40 * 16, 256, 0, stream>>>(p, out + fa_off[l], sizes[l], shifts[l]);
    k_aggn<<<40 * 8, 256, 0, stream>>>(vt, p, aggn);
    k_aggred<<<BS * VD * HW / 256, 256, 0, stream>>>(
        aggn, f16_all + (size_t)l * 4 * CIN * HW);
  }

  // Stage 3: combine
  k_g16_all<<<5 * 4 * 32, 256, 0, stream>>>(f16_all, cw, gamma, g16_all);
  for (int l = 0; l < 5; ++l) {
    int S = sizes[l], sh = shifts[l], SS = S * S;
    int chunks = (SS + 255) / 256;
    k_out<<<BS * 8 * chunks, 256, 0, stream>>>(
        feat[l], cw, g16_all + (size_t)l * 4 * CIN * HW, cb + l * CIN,
        out + out_off[l], S, sh, chunks);
  }
}

// Round 5
// 650.105 us; speedup vs baseline: 1.8811x; 1.8811x over previous
//
#include <hip/hip_runtime.h>

// Problem constants
constexpr int CIN   = 256;   // feature channels
constexpr int KD    = 32;    // key dim
constexpr int VD    = 128;   // value dim
constexpr int NCLS  = 10;
constexpr int BS    = 4;
constexpr int HW    = 256;   // 16*16
constexpr int NJOBS = 30;    // 5 levels * 4 images + 10 template images
constexpr float BNC = 0.9999950000374997f; // 1/sqrt(1+1e-5)

static __device__ __forceinline__ int imin(int a, int b) { return a < b ? a : b; }

// ---------------------------------------------------------------------------
// Unified conv3x3 partial (levels + templates in one grid), NIMG=2 images per
// weight-load. 15 groups: g<10 -> level images {g*2,g*2+1} w/ per-level weights
// (level = g>>1); g>=10 -> template images {(g-10)*2, +1} w/ shared weights.
// grid = 15 * (OC/8) * KS.  part[((ks*NJOBS + job)*OC + oc)*HW + px].
template<int KS_, int OC_>
__global__ __launch_bounds__(256) void k_conv(
    const float* __restrict__ fr_all, const float* __restrict__ att,
    const float* __restrict__ w_lvl, const float* __restrict__ w_tmpl,
    float* __restrict__ part) {
  constexpr int CPB = 256 / KS_;
  constexpr int NT  = OC_ / 8;
  int g   = blockIdx.x / (NT * KS_);
  int rem = blockIdx.x % (NT * KS_);
  int ks  = rem / NT, ocg = rem % NT;
  int tid = threadIdx.x;
  int y = tid >> 4, x = tid & 15;

  __shared__ float sm[2][4][18][18];   // 10.4 KB
  for (int i = tid; i < 2 * 4 * 324; i += 256) ((float*)sm)[i] = 0.f;

  float acc[2][8] = {};
  bool lvl = g < 10;
  const float* inb = (lvl ? fr_all + (size_t)(g * 2) * CIN * HW
                          : att + (size_t)((g - 10) * 2) * CIN * HW)
                     + (size_t)ks * CPB * HW;
  const float* wb = (lvl ? w_lvl + (size_t)(g >> 1) * OC_ * CIN * 9 : w_tmpl)
                    + ((size_t)(ocg * 8) * CIN + ks * CPB) * 9;
  int job = lvl ? g * 2 : 20 + (g - 10) * 2;

  for (int ch = 0; ch < CPB / 4; ++ch) {
    __syncthreads();   // covers zero-fill on first iter, compute on later iters
#pragma unroll
    for (int im = 0; im < 2; ++im)
#pragma unroll
      for (int pch = 0; pch < 4; ++pch)
        sm[im][pch][y + 1][x + 1] = inb[((size_t)im * CIN + ch * 4 + pch) * HW + tid];
    __syncthreads();
#pragma unroll
    for (int pch = 0; pch < 4; ++pch) {
      float r[2][9];
#pragma unroll
      for (int im = 0; im < 2; ++im) {
        r[im][0] = sm[im][pch][y][x];     r[im][1] = sm[im][pch][y][x + 1];     r[im][2] = sm[im][pch][y][x + 2];
        r[im][3] = sm[im][pch][y + 1][x]; r[im][4] = sm[im][pch][y + 1][x + 1]; r[im][5] = sm[im][pch][y + 1][x + 2];
        r[im][6] = sm[im][pch][y + 2][x]; r[im][7] = sm[im][pch][y + 2][x + 1]; r[im][8] = sm[im][pch][y + 2][x + 2];
      }
      int c = ch * 4 + pch;
#pragma unroll
      for (int o = 0; o < 8; ++o) {
        const float* wp = wb + ((size_t)o * CIN + c) * 9;   // wave-uniform -> s_load
        float w0 = wp[0], w1 = wp[1], w2 = wp[2], w3 = wp[3], w4 = wp[4],
              w5 = wp[5], w6 = wp[6], w7 = wp[7], w8 = wp[8];
#pragma unroll
        for (int im = 0; im < 2; ++im)
          acc[im][o] += w0 * r[im][0] + w1 * r[im][1] + w2 * r[im][2]
                      + w3 * r[im][3] + w4 * r[im][4] + w5 * r[im][5]
                      + w6 * r[im][6] + w7 * r[im][7] + w8 * r[im][8];
      }
    }
  }
#pragma unroll
  for (int im = 0; im < 2; ++im)
    for (int o = 0; o < 8; ++o)
      part[(((size_t)ks * NJOBS + job + im) * OC_ + ocg * 8 + o) * HW + tid] = acc[im][o];
}

// reduce over KS partials, add bias, scale. total = NJOBS*OC*HW.
template<int KS_>
__global__ __launch_bounds__(256) void k_conv_red(
    const float* __restrict__ part,
    const float* __restrict__ bias_lvl, const float* __restrict__ bias_tmpl,
    float* __restrict__ out_lvl, float* __restrict__ out_tmpl,
    int OC, int outC_lvl, float scale_lvl) {
  int idx = blockIdx.x * 256 + threadIdx.x;
  int px  = idx & 255;
  int oc  = (idx >> 8) % OC;
  int job = idx / (OC * HW);
  size_t stride = (size_t)NJOBS * OC * HW;
  const float* pp = part + idx;
  float s = 0.f;
#pragma unroll
  for (int k = 0; k < KS_; ++k) s += pp[k * stride];
  if (job < 20)
    out_lvl[((size_t)job * outC_lvl + oc) * HW + px] =
        (s + bias_lvl[(job >> 2) * OC + oc]) * scale_lvl;
  else
    out_tmpl[((size_t)(job - 20) * OC + oc) * HW + px] = s + bias_tmpl[oc];
}

// ---------------------------------------------------------------------------
// resize all 5 levels' features to 16x16: fr_all[l*4+b][c][256].
__global__ __launch_bounds__(256) void k_resize_all(
    const float* __restrict__ f0, const float* __restrict__ f1,
    const float* __restrict__ f2, const float* __restrict__ f3,
    const float* __restrict__ f4, float* __restrict__ fr_all) {
  int plane = blockIdx.x, px = threadIdx.x;
  int l = plane >> 10, pb = plane & 1023;
  int S = 64 >> l;
  const float* fin;
  switch (l) {
    case 0: fin = f0; break; case 1: fin = f1; break; case 2: fin = f2; break;
    case 3: fin = f3; break; default: fin = f4; break;
  }
  fin += (size_t)pb * S * S;
  int Y = px >> 4, X = px & 15;
  float cyf = (float)(Y * (S - 1)) / 15.0f;
  int ylo = imin((int)cyf, S - 2); float fy = cyf - (float)ylo;
  float cxf = (float)(X * (S - 1)) / 15.0f;
  int xlo = imin((int)cxf, S - 2); float fx = cxf - (float)xlo;
  float v0 = fin[ylo * S + xlo],       v1 = fin[ylo * S + xlo + 1];
  float v2 = fin[(ylo + 1) * S + xlo], v3 = fin[(ylo + 1) * S + xlo + 1];
  fr_all[(size_t)plane * HW + px] =
      (1.f - fy) * ((1.f - fx) * v0 + fx * v1) + fy * ((1.f - fx) * v2 + fx * v3);
}

// ---------------------------------------------------------------------------
// Fused p: scores + softmax(over i) + normalized write, one level.
// grid = 40*8 (bn, jt of 32 j); block = 256 = 8 iq-groups x 32 jl.
__global__ __launch_bounds__(256) void k_p_fused(
    const float* __restrict__ kq_lvl, const float* __restrict__ ktb,
    float* __restrict__ p) {
  int bn = blockIdx.x >> 3, jt = blockIdx.x & 7;
  int b = bn / NCLS, n = bn % NCLS;
  int t = threadIdx.x;
  int iq = t >> 5, jl = t & 31;
  int j = jt * 32 + jl;

  __shared__ float kqs[KD][HW];   // 32 KB; reused for stats after compute
  float ktr[KD];
#pragma unroll
  for (int k = 0; k < KD; ++k) ktr[k] = ktb[((size_t)n * KD + k) * HW + j];
  const float* kqb = kq_lvl + (size_t)b * KD * HW;
  for (int s = t; s < KD * HW; s += 256) ((float*)kqs)[s] = kqb[s];
  __syncthreads();

  float v[32];
#pragma unroll
  for (int ii = 0; ii < 32; ++ii) v[ii] = 0.f;
  for (int k = 0; k < KD; ++k) {
    float a = ktr[k];
    const float4* q4 = (const float4*)&kqs[k][iq * 32];
#pragma unroll
    for (int q = 0; q < 8; ++q) {
      float4 u = q4[q];
      v[q * 4 + 0] += u.x * a; v[q * 4 + 1] += u.y * a;
      v[q * 4 + 2] += u.z * a; v[q * 4 + 3] += u.w * a;
    }
  }
  float ml = -1e30f;
#pragma unroll
  for (int ii = 0; ii < 32; ++ii) ml = fmaxf(ml, v[ii]);
  float sl = 0.f;
#pragma unroll
  for (int ii = 0; ii < 32; ++ii) sl += __expf(v[ii] - ml);

  __syncthreads();                 // all waves done reading kqs
  float* red = (float*)kqs;        // [0..255]=m, [256..511]=s
  red[iq * 32 + jl] = ml;
  red[256 + iq * 32 + jl] = sl;
  __syncthreads();
  float M = -1e30f;
#pragma unroll
  for (int q = 0; q < 8; ++q) M = fmaxf(M, red[q * 32 + jl]);
  float S = 0.f;
#pragma unroll
  for (int q = 0; q < 8; ++q) S += red[256 + q * 32 + jl] * __expf(red[q * 32 + jl] - M);
  float inv = 1.0f / S;

  float* pb = p + (size_t)bn * HW * HW + j;
#pragma unroll
  for (int ii = 0; ii < 32; ++ii)
    pb[(size_t)(iq * 32 + ii) * HW] = __expf(v[ii] - M) * inv;
}

// ---------------------------------------------------------------------------
// fa via LDS transpose: block = (bn, jg of 16 j's). Stage p[:,16j] tile,
// emit 16*S*S pixels with coalesced float4 stores.
__global__ __launch_bounds__(256) void k_fa_t(
    const float* __restrict__ p, float* __restrict__ out, int S, int shift) {
  int bn = blockIdx.x >> 4, jg = blockIdx.x & 15;
  int tid = threadIdx.x;
  __shared__ float ld[256][17];
  const float* pb = p + (size_t)bn * HW * HW + jg * 16;
  for (int t = tid; t < 4096; t += 256)
    ld[t >> 4][t & 15] = pb[(size_t)(t >> 4) * HW + (t & 15)];
  __syncthreads();

  int SS = S * S, tot = SS << 4;
  for (int base = tid * 4; base < tot; base += 1024) {
    int jj = base >> (2 * shift);
    int rest = base & (SS - 1);
    int X0 = rest & (S - 1), Y = rest >> shift;
    float cyf = (float)(Y * 15) / (float)(S - 1);
    int ylo = imin((int)cyf, 14); float fy = cyf - (float)ylo;
    float4 r; float* rr = (float*)&r;
#pragma unroll
    for (int t4 = 0; t4 < 4; ++t4) {
      int X = X0 + t4;
      float cxf = (float)(X * 15) / (float)(S - 1);
      int xlo = imin((int)cxf, 14); float fx = cxf - (float)xlo;
      int i00 = ylo * 16 + xlo;
      float v0 = ld[i00][jj],      v1 = ld[i00 + 1][jj];
      float v2 = ld[i00 + 16][jj], v3 = ld[i00 + 17][jj];
      rr[t4] = (1.f - fy) * ((1.f - fx) * v0 + fx * v1)
             + fy * ((1.f - fx) * v2 + fx * v3);
    }
    *(float4*)(out + ((size_t)bn * HW + jg * 16 + jj) * SS + rest) = r;
  }
}

// ---------------------------------------------------------------------------
// aggn[bn,c,j] = sum_i vt[n,c,i] * p[bn,i,j]. grid = 40*16 (ctile 8)
__global__ __launch_bounds__(256) void k_aggn(
    const float* __restrict__ vt, const float* __restrict__ p, float* __restrict__ aggn) {
  int blk = blockIdx.x;
  int ct = blk & 15, bn = blk >> 4;
  int n = bn % NCLS;
  int j = threadIdx.x;
  __shared__ float vts[8][HW];
  for (int c = 0; c < 8; ++c) vts[c][j] = vt[((size_t)n * VD + ct * 8 + c) * HW + j];
  __syncthreads();
  float acc[8] = {};
  const float* pp = p + (size_t)bn * HW * HW + j;
  for (int i = 0; i < HW; ++i) {
    float pv = pp[(size_t)i * HW];
#pragma unroll
    for (int c = 0; c < 8; ++c) acc[c] += vts[c][i] * pv;
  }
  for (int c = 0; c < 8; ++c)
    aggn[((size_t)bn * VD + ct * 8 + c) * HW + j] = acc[c];
}

// f16[b, 128+c, j] = sum_n aggn[b,n,c,j].  total = BS*VD*HW = 131072
__global__ __launch_bounds__(256) void k_aggred(
    const float* __restrict__ aggn, float* __restrict__ f16) {
  int idx = blockIdx.x * 256 + threadIdx.x;
  int j = idx & 255;
  int c = (idx >> 8) & 127;
  int b = idx >> 15;
  float s = 0.f;
#pragma unroll
  for (int n = 0; n < NCLS; ++n)
    s += aggn[(((size_t)b * NCLS + n) * VD + c) * HW + j];
  f16[((size_t)b * CIN + VD + c) * HW + j] = s;
}

// ---------------------------------------------------------------------------
// g16_all[l,b,oc,j] = sum_c cw[oc,256+c]*(gamma[l,c]*BNC)*f16_all[l,b,c,j]
// grid = 5*4*32 (8 oc per block)
__global__ __launch_bounds__(256) void k_g16_all(
    const float* __restrict__ f16_all, const float* __restrict__ cw,
    const float* __restrict__ gamma, float* __restrict__ g16_all) {
  int blk = blockIdx.x;
  int l = blk >> 7, b = (blk >> 5) & 3, ocg = blk & 31;
  int j = threadIdx.x;
  const float* f16 = f16_all + (size_t)(l * 4 + b) * CIN * HW;
  const float* gm  = gamma + l * CIN;
  float acc[8] = {};
  for (int c = 0; c < CIN; ++c) {
    float fv = f16[(size_t)c * HW + j] * (gm[c] * BNC);
#pragma unroll
    for (int o = 0; o < 8; ++o)
      acc[o] += cw[(size_t)(ocg * 8 + o) * 512 + 256 + c] * fv;
  }
  for (int o = 0; o < 8; ++o)
    g16_all[((size_t)(l * 4 + b) * CIN + ocg * 8 + o) * HW + j] = acc[o];
}

// cb[l,oc] = combine_b[oc] + sum_c cw[oc,256+c]*beta[l,c].  grid=5, block=256
__global__ __launch_bounds__(256) void k_cb(
    const float* __restrict__ cw, const float* __restrict__ cbias,
    const float* __restrict__ beta, float* __restrict__ cb) {
  int l = blockIdx.x, oc = threadIdx.x;
  float s = cbias[oc];
  for (int c = 0; c < CIN; ++c)
    s += cw[(size_t)oc * 512 + 256 + c] * beta[l * CIN + c];
  cb[l * CIN + oc] = s;
}

// ---------------------------------------------------------------------------
// Merged final conv across all 5 levels. Per-level block counts:
// chunks={16,4,1,1,1} -> blocks = 32*chunks = {512,128,32,32,32}, cum below.
__global__ __launch_bounds__(256) void k_out_all(
    const float* __restrict__ f0, const float* __restrict__ f1,
    const float* __restrict__ f2, const float* __restrict__ f3,
    const float* __restrict__ f4, const float* __restrict__ cw,
    const float* __restrict__ g16_all, const float* __restrict__ cb_all,
    float* __restrict__ out) {
  constexpr int cum[5]    = {512, 640, 672, 704, 736};
  constexpr int chn[5]    = {16, 4, 1, 1, 1};
  constexpr int shf[5]    = {6, 5, 4, 3, 2};
  constexpr size_t ooff[5] = {0, 4194304, 5242880, 5505024, 5570560};
  int blk = blockIdx.x;
  int l = 0;
#pragma unroll
  for (int q = 0; q < 4; ++q) if (blk >= cum[q]) l = q + 1;
  int base = (l == 0) ? 0 : cum[l - 1];
  int local = blk - base;
  int chunks = chn[l], shift = shf[l];
  int S = 64 >> l, SS = S * S;
  int ch = local % chunks;
  int t  = local / chunks;
  int ocg = t & 7, b = t >> 3;
  int pix = ch * 256 + threadIdx.x;
  if (pix >= SS) return;
  const float* f;
  switch (l) {
    case 0: f = f0; break; case 1: f = f1; break; case 2: f = f2; break;
    case 3: f = f3; break; default: f = f4; break;
  }
  int X = pix & (S - 1), Y = pix >> shift;
  float acc[32] = {};
  const float* fb = f + (size_t)b * CIN * SS + pix;
  for (int c = 0; c < CIN; ++c) {
    float fv = fb[(size_t)c * SS];
#pragma unroll
    for (int o = 0; o < 32; ++o)
      acc[o] += cw[(size_t)(ocg * 32 + o) * 512 + c] * fv;
  }
  float cyf = (float)(Y * 15) / (float)(S - 1);
  int ylo = imin((int)cyf, 14); float fy = cyf - (float)ylo;
  float cxf = (float)(X * 15) / (float)(S - 1);
  int xlo = imin((int)cxf, 14); float fx = cxf - (float)xlo;
  const float* gb = g16_all + ((size_t)(l * 4 + b) * CIN + ocg * 32) * HW + ylo * 16 + xlo;
  const float* cb = cb_all + l * CIN;
#pragma unroll
  for (int o = 0; o < 32; ++o) {
    const float* g = gb + (size_t)o * HW;
    float v0 = g[0], v1 = g[1], v2 = g[16], v3 = g[17];
    float bil = (1.f - fy) * ((1.f - fx) * v0 + fx * v1)
              + fy * ((1.f - fx) * v2 + fx * v3);
    out[ooff[l] + ((size_t)b * CIN + ocg * 32 + o) * SS + pix] = acc[o] + bil + cb[ocg * 32 + o];
  }
}

// ===========================================================================
extern "C" void kernel_launch(void* const* d_in, const int* in_sizes, int n_in,
                              void* d_out, int out_size, void* d_ws, size_t ws_size,
                              hipStream_t stream) {
  const float* feat[5];
  for (int l = 0; l < 5; ++l) feat[l] = (const float*)d_in[l];
  const float* att   = (const float*)d_in[5];
  const float* ktw   = (const float*)d_in[6];
  const float* ktb   = (const float*)d_in[7];
  const float* vtw   = (const float*)d_in[8];
  const float* vtb   = (const float*)d_in[9];
  const float* kqw   = (const float*)d_in[10];
  const float* kqb   = (const float*)d_in[11];
  const float* vqw   = (const float*)d_in[12];
  const float* vqb   = (const float*)d_in[13];
  const float* gamma = (const float*)d_in[14];
  const float* beta  = (const float*)d_in[15];
  const float* cw    = (const float*)d_in[16];
  const float* cbias = (const float*)d_in[17];
  float* out = (float*)d_out;

  // workspace layout (floats), total ~9.14M fl = 36.6 MB
  float* ws      = (float*)d_ws;
  float* kqall   = ws;                    // [30][32][256]      = 245760
  float* vt      = kqall  + 245760;       // [10][128][256]     = 327680
  float* fr_all  = vt     + 327680;       // [20][256][256]     = 1310720
  float* f16_all = fr_all + 1310720;      // [20][256][256]     = 1310720
  float* g16_all = f16_all+ 1310720;      // [20][256][256]     = 1310720
  float* cb      = g16_all+ 1310720;      // [5][256]           = 1280
  float* p       = cb     + 1280;         // [40][256][256]     = 2621440
  float* aggn    = p      + 2621440;      // [40][128][256]     = 1310720
  float* part    = p;                     // conv partials alias p+aggn (3932160 fl),
                                          // time-shared: convK->redK->convV->redV

  size_t fa_off[5];
  {
    size_t off = 5586944;  // total outs
    static const int sizes[5] = {64, 32, 16, 8, 4};
    for (int l = 0; l < 5; ++l) { fa_off[l] = off; off += (size_t)BS * NCLS * HW * sizes[l] * sizes[l]; }
  }
  static const int sizes[5]  = {64, 32, 16, 8, 4};
  static const int shifts[5] = {6, 5, 4, 3, 2};

  // Stage 1: resize + all convs
  k_resize_all<<<5 * 4 * 256, 256, 0, stream>>>(
      feat[0], feat[1], feat[2], feat[3], feat[4], fr_all);
  // K conv: KS=16, OC=32 -> 15*4*16 = 960 blocks. partK = 16*30*32*256 = 3.93M fl.
  k_conv<16, 32><<<960, 256, 0, stream>>>(fr_all, att, kqw, ktw, part);
  k_conv_red<16><<<960, 256, 0, stream>>>(
      part, kqb, ktb, kqall, kqall + 20 * KD * HW, KD, KD, 1.f);
  // V conv: KS=4, OC=128 -> 15*16*4 = 960 blocks. partV = 4*30*128*256 = 3.93M fl.
  k_conv<4, 128><<<960, 256, 0, stream>>>(fr_all, att, vqw, vtw, part);
  k_conv_red<4><<<3840, 256, 0, stream>>>(
      part, vqb, vtb, f16_all, vt, VD, CIN, (float)NCLS);
  k_cb<<<5, 256, 0, stream>>>(cw, cbias, beta, cb);

  // Stage 2: per-level p-chain (p buffer reused)
  for (int l = 0; l < 5; ++l) {
    k_p_fused<<<40 * 8, 256, 0, stream>>>(
        kqall + (size_t)l * 4 * KD * HW, kqall + 20 * KD * HW, p);
    k_fa_t<<<40 * 16, 256, 0, stream>>>(p, out + fa_off[l], sizes[l], shifts[l]);
    k_aggn<<<40 * 16, 256, 0, stream>>>(vt, p, aggn);
    k_aggred<<<BS * VD * HW / 256, 256, 0, stream>>>(
        aggn, f16_all + (size_t)l * 4 * CIN * HW);
  }

  // Stage 3: combine (merged across levels)
  k_g16_all<<<5 * 4 * 32, 256, 0, stream>>>(f16_all, cw, gamma, g16_all);
  k_out_all<<<736, 256, 0, stream>>>(
      feat[0], feat[1], feat[2], feat[3], feat[4], cw, g16_all, cb, out);
}

// Round 6
// 577.016 us; speedup vs baseline: 2.1194x; 1.1267x over previous
//
#include <hip/hip_runtime.h>

// Problem constants
constexpr int CIN   = 256;   // feature channels
constexpr int KD    = 32;    // key dim
constexpr int VD    = 128;   // value dim
constexpr int NCLS  = 10;
constexpr int BS    = 4;
constexpr int HW    = 256;   // 16*16
constexpr float BNC = 0.9999950000374997f; // 1/sqrt(1+1e-5)

typedef unsigned short u16;
typedef __attribute__((ext_vector_type(8))) __bf16 bf8v;
typedef __attribute__((ext_vector_type(4))) float f4v;

static __device__ __forceinline__ int imin(int a, int b) { return a < b ? a : b; }

static __device__ __forceinline__ u16 f2bf(float v) {
  union { float f; unsigned u; } x; x.f = v;
  unsigned r = x.u + 0x7FFFu + ((x.u >> 16) & 1u);
  return (u16)(r >> 16);
}
static __device__ __forceinline__ float bf2f(u16 h) {
  union { unsigned u; float f; } x; x.u = ((unsigned)h) << 16;
  return x.f;
}

static __device__ __forceinline__ f4v mfma16(bf8v a, bf8v b, f4v c) {
  return __builtin_amdgcn_mfma_f32_16x16x32_bf16(a, b, c, 0, 0, 0);
}

// ---------------------------------------------------------------------------
// Prep weights into MFMA-A fragment order, split bf16 hi/lo.
// k' = t*256 + c; chunk kc: t = kc>>3, c0 = (kc&7)*32. Per (set,ot,kc):
// [2][64 lanes][8] bf16 (hi slab then lo slab = 1024 u16).
// V grps: sid(6: 5 lvl + tmpl) x ot(8) x kc(72) = 3456; K grps: 6 x 2 x 72 = 864.
__global__ __launch_bounds__(256) void k_prep_w(
    const float* __restrict__ vqw, const float* __restrict__ vtw,
    const float* __restrict__ kqw, const float* __restrict__ ktw,
    u16* __restrict__ Awv, u16* __restrict__ Awk) {
  int gid = blockIdx.x * 256 + threadIdx.x;
  int lane = gid & 63;
  int grp = gid >> 6;
  const float* src; u16* dst; int kc;
  if (grp < 3456) {
    kc = grp % 72; int ot = (grp / 72) % 8; int sid = grp / (72 * 8);
    src = (sid < 5 ? vqw + (size_t)sid * VD * 2304 : vtw) + (size_t)(ot * 16 + (lane & 15)) * 2304;
    dst = Awv + (size_t)grp * 1024;
  } else {
    int g2 = grp - 3456;
    kc = g2 % 72; int ot = (g2 / 72) % 2; int sid = g2 / 144;
    src = (sid < 5 ? kqw + (size_t)sid * KD * 2304 : ktw) + (size_t)(ot * 16 + (lane & 15)) * 2304;
    dst = Awk + (size_t)g2 * 1024;
  }
  int q0 = (lane >> 4) * 8;
  int t = kc >> 3, c0 = (kc & 7) * 32;
#pragma unroll
  for (int i = 0; i < 8; ++i) {
    int c = c0 + q0 + i;
    float v = src[c * 9 + t];
    u16 h = f2bf(v);
    u16 lo = f2bf(v - bf2f(h));
    dst[lane * 8 + i] = h;
    dst[512 + lane * 8 + i] = lo;
  }
}

// ---------------------------------------------------------------------------
// Prep padded split-bf16 inputs, channel-interleaved: X[img][y'][x'][2][256].
// img<20: bilinear-resized level features (l=img>>2, b=img&3); img>=20: att.
// Border ring (y'=0/17, x'=0/17) = 0. grid = 30*18 (img,y'), block = 256 (c).
__global__ __launch_bounds__(256) void k_prep_x(
    const float* __restrict__ f0, const float* __restrict__ f1,
    const float* __restrict__ f2, const float* __restrict__ f3,
    const float* __restrict__ f4, const float* __restrict__ att,
    u16* __restrict__ X) {
  int img = blockIdx.x / 18, y1 = blockIdx.x % 18;
  int c = threadIdx.x;
  u16* xb = X + ((size_t)img * 18 + y1) * 18 * 512;
  const float* fin = nullptr;
  int S = 16, ylo = 0, xshift = 0;
  float fy = 0.f;
  bool inner_y = (y1 >= 1 && y1 <= 16);
  if (img < 20 && inner_y) {
    int l = img >> 2, b = img & 3;
    S = 64 >> l;
    switch (l) {
      case 0: fin = f0; break; case 1: fin = f1; break; case 2: fin = f2; break;
      case 3: fin = f3; break; default: fin = f4; break;
    }
    fin += ((size_t)b * CIN + c) * S * S;
    int y = y1 - 1;
    float cyf = (float)(y * (S - 1)) / 15.0f;
    ylo = imin((int)cyf, S - 2); fy = cyf - (float)ylo;
  }
  for (int x1 = 0; x1 < 18; ++x1) {
    float v = 0.f;
    if (inner_y && x1 >= 1 && x1 <= 16) {
      int x = x1 - 1;
      if (img < 20) {
        float cxf = (float)(x * (S - 1)) / 15.0f;
        int xlo = imin((int)cxf, S - 2); float fx = cxf - (float)xlo;
        const float* pb = fin + ylo * S + xlo;
        float v0 = pb[0], v1 = pb[1], v2 = pb[S], v3 = pb[S + 1];
        v = (1.f - fy) * ((1.f - fx) * v0 + fx * v1) + fy * ((1.f - fx) * v2 + fx * v3);
      } else {
        v = att[(((size_t)(img - 20) * CIN + c) << 8) + (y1 - 1) * 16 + x];
      }
    }
    u16 h = f2bf(v);
    u16 lo = f2bf(v - bf2f(h));
    xb[x1 * 512 + c] = h;
    xb[x1 * 512 + 256 + c] = lo;
  }
}

// ---------------------------------------------------------------------------
// MFMA conv: one wave = (img, 16-oc tile, 2 pixel rows). Full K=2304 per wave
// (9 taps x 8 chunks of 32 chans), bf16 split (3 MFMA per chunk per row).
// V jobs: 30 img x 8 ot x 8 yp = 1920; K jobs: 30 x 2 x 8 = 480. grid=600x256.
__global__ __launch_bounds__(256) void k_conv_mfma(
    const u16* __restrict__ X, const u16* __restrict__ Awv, const u16* __restrict__ Awk,
    float* __restrict__ kqall, float* __restrict__ vt, float* __restrict__ f16_all,
    const float* __restrict__ vqb, const float* __restrict__ vtb,
    const float* __restrict__ kqb, const float* __restrict__ ktb) {
  int wid = blockIdx.x * 4 + (threadIdx.x >> 6);
  int lane = threadIdx.x & 63;
  bool isV = wid < 1920;
  int img, ot, yp;
  if (isV) { img = wid >> 6; int r = wid & 63; ot = r >> 3; yp = r & 7; }
  else     { int j = wid - 1920; img = j >> 4; int r = j & 15; ot = r >> 3; yp = r & 7; }
  int wset = img < 20 ? (img >> 2) : 5;

  const u16* Ab = isV ? Awv + ((size_t)(wset * 8 + ot)) * 72 * 1024
                      : Awk + ((size_t)(wset * 2 + ot)) * 72 * 1024;
  const u16* Xb = X + (size_t)img * 165888;   // 18*18*512
  int xcol = lane & 15, kg = lane >> 4;
  int y0 = yp * 2, y1 = y0 + 1;

  f4v acc0 = {0.f, 0.f, 0.f, 0.f}, acc1 = {0.f, 0.f, 0.f, 0.f};
  for (int t = 0; t < 9; ++t) {
    int dy = (t >= 6) ? 2 : (t >= 3 ? 1 : 0);
    int dx = t - dy * 3;
    const u16* Xr0 = Xb + ((size_t)((y0 + dy) * 18 + dx + xcol)) * 512 + kg * 8;
    const u16* Xr1 = Xb + ((size_t)((y1 + dy) * 18 + dx + xcol)) * 512 + kg * 8;
    const u16* Ak = Ab + (size_t)t * 8 * 1024 + lane * 8;
#pragma unroll
    for (int cc = 0; cc < 8; ++cc) {
      bf8v ah = *reinterpret_cast<const bf8v*>(Ak + cc * 1024);
      bf8v al = *reinterpret_cast<const bf8v*>(Ak + cc * 1024 + 512);
      const u16* b0 = Xr0 + cc * 32;
      const u16* b1 = Xr1 + cc * 32;
      bf8v bh0 = *reinterpret_cast<const bf8v*>(b0);
      bf8v bl0 = *reinterpret_cast<const bf8v*>(b0 + 256);
      bf8v bh1 = *reinterpret_cast<const bf8v*>(b1);
      bf8v bl1 = *reinterpret_cast<const bf8v*>(b1 + 256);
      acc0 = mfma16(ah, bh0, acc0);
      acc0 = mfma16(ah, bl0, acc0);
      acc0 = mfma16(al, bh0, acc0);
      acc1 = mfma16(ah, bh1, acc1);
      acc1 = mfma16(ah, bl1, acc1);
      acc1 = mfma16(al, bh1, acc1);
    }
  }

  // Epilogue. D layout: oc_local = kg*4 + i, px_col = lane&15.
  float scale = 1.f;
  const float* bias;
  float* dst;
  int ocbase = ot * 16;
  if (isV) {
    if (img < 20) { dst = f16_all + ((size_t)img * CIN + ocbase) * HW; bias = vqb + wset * VD + ocbase; scale = (float)NCLS; }
    else          { dst = vt + ((size_t)(img - 20) * VD + ocbase) * HW; bias = vtb + ocbase; }
  } else {
    if (img < 20) { dst = kqall + ((size_t)img * KD + ocbase) * HW; bias = kqb + wset * KD + ocbase; }
    else          { dst = kqall + (size_t)20 * KD * HW + ((size_t)(img - 20) * KD + ocbase) * HW; bias = ktb + ocbase; }
  }
#pragma unroll
  for (int i = 0; i < 4; ++i) {
    int ocl = kg * 4 + i;
    float bv = bias[ocl];
    dst[(size_t)ocl * HW + y0 * 16 + xcol] = (acc0[i] + bv) * scale;
    dst[(size_t)ocl * HW + y1 * 16 + xcol] = (acc1[i] + bv) * scale;
  }
}

// ---------------------------------------------------------------------------
// Fused p: scores + softmax(over i) + normalized write, one level.
// grid = 40*8 (bn, jt of 32 j); block = 256 = 8 iq-groups x 32 jl.
__global__ __launch_bounds__(256) void k_p_fused(
    const float* __restrict__ kq_lvl, const float* __restrict__ ktb,
    float* __restrict__ p) {
  int bn = blockIdx.x >> 3, jt = blockIdx.x & 7;
  int b = bn / NCLS, n = bn % NCLS;
  int t = threadIdx.x;
  int iq = t >> 5, jl = t & 31;
  int j = jt * 32 + jl;

  __shared__ float kqs[KD][HW];   // 32 KB; reused for stats after compute
  float ktr[KD];
#pragma unroll
  for (int k = 0; k < KD; ++k) ktr[k] = ktb[((size_t)n * KD + k) * HW + j];
  const float* kqb = kq_lvl + (size_t)b * KD * HW;
  for (int s = t; s < KD * HW; s += 256) ((float*)kqs)[s] = kqb[s];
  __syncthreads();

  float v[32];
#pragma unroll
  for (int ii = 0; ii < 32; ++ii) v[ii] = 0.f;
  for (int k = 0; k < KD; ++k) {
    float a = ktr[k];
    const float4* q4 = (const float4*)&kqs[k][iq * 32];
#pragma unroll
    for (int q = 0; q < 8; ++q) {
      float4 u = q4[q];
      v[q * 4 + 0] += u.x * a; v[q * 4 + 1] += u.y * a;
      v[q * 4 + 2] += u.z * a; v[q * 4 + 3] += u.w * a;
    }
  }
  float ml = -1e30f;
#pragma unroll
  for (int ii = 0; ii < 32; ++ii) ml = fmaxf(ml, v[ii]);
  float sl = 0.f;
#pragma unroll
  for (int ii = 0; ii < 32; ++ii) sl += __expf(v[ii] - ml);

  __syncthreads();                 // all waves done reading kqs
  float* red = (float*)kqs;        // [0..255]=m, [256..511]=s
  red[iq * 32 + jl] = ml;
  red[256 + iq * 32 + jl] = sl;
  __syncthreads();
  float M = -1e30f;
#pragma unroll
  for (int q = 0; q < 8; ++q) M = fmaxf(M, red[q * 32 + jl]);
  float S = 0.f;
#pragma unroll
  for (int q = 0; q < 8; ++q) S += red[256 + q * 32 + jl] * __expf(red[q * 32 + jl] - M);
  float inv = 1.0f / S;

  float* pb = p + (size_t)bn * HW * HW + j;
#pragma unroll
  for (int ii = 0; ii < 32; ++ii)
    pb[(size_t)(iq * 32 + ii) * HW] = __expf(v[ii] - M) * inv;
}

// ---------------------------------------------------------------------------
// fa via LDS transpose: block = (bn, jg of 16 j's). Stage p[:,16j] tile,
// emit 16*S*S pixels with coalesced float4 stores.
__global__ __launch_bounds__(256) void k_fa_t(
    const float* __restrict__ p, float* __restrict__ out, int S, int shift) {
  int bn = blockIdx.x >> 4, jg = blockIdx.x & 15;
  int tid = threadIdx.x;
  __shared__ float ld[256][17];
  const float* pb = p + (size_t)bn * HW * HW + jg * 16;
  for (int t = tid; t < 4096; t += 256)
    ld[t >> 4][t & 15] = pb[(size_t)(t >> 4) * HW + (t & 15)];
  __syncthreads();

  int SS = S * S, tot = SS << 4;
  for (int base = tid * 4; base < tot; base += 1024) {
    int jj = base >> (2 * shift);
    int rest = base & (SS - 1);
    int X0 = rest & (S - 1), Y = rest >> shift;
    float cyf = (float)(Y * 15) / (float)(S - 1);
    int ylo = imin((int)cyf, 14); float fy = cyf - (float)ylo;
    float4 r; float* rr = (float*)&r;
#pragma unroll
    for (int t4 = 0; t4 < 4; ++t4) {
      int X = X0 + t4;
      float cxf = (float)(X * 15) / (float)(S - 1);
      int xlo = imin((int)cxf, 14); float fx = cxf - (float)xlo;
      int i00 = ylo * 16 + xlo;
      float v0 = ld[i00][jj],      v1 = ld[i00 + 1][jj];
      float v2 = ld[i00 + 16][jj], v3 = ld[i00 + 17][jj];
      rr[t4] = (1.f - fy) * ((1.f - fx) * v0 + fx * v1)
             + fy * ((1.f - fx) * v2 + fx * v3);
    }
    *(float4*)(out + ((size_t)bn * HW + jg * 16 + jj) * SS + rest) = r;
  }
}

// ---------------------------------------------------------------------------
// aggn[bn,c,j] = sum_i vt[n,c,i] * p[bn,i,j]. grid = 40*16 (ctile 8)
__global__ __launch_bounds__(256) void k_aggn(
    const float* __restrict__ vt, const float* __restrict__ p, float* __restrict__ aggn) {
  int blk = blockIdx.x;
  int ct = blk & 15, bn = blk >> 4;
  int n = bn % NCLS;
  int j = threadIdx.x;
  __shared__ float vts[8][HW];
  for (int c = 0; c < 8; ++c) vts[c][j] = vt[((size_t)n * VD + ct * 8 + c) * HW + j];
  __syncthreads();
  float acc[8] = {};
  const float* pp = p + (size_t)bn * HW * HW + j;
  for (int i = 0; i < HW; ++i) {
    float pv = pp[(size_t)i * HW];
#pragma unroll
    for (int c = 0; c < 8; ++c) acc[c] += vts[c][i] * pv;
  }
  for (int c = 0; c < 8; ++c)
    aggn[((size_t)bn * VD + ct * 8 + c) * HW + j] = acc[c];
}

// f16[b, 128+c, j] = sum_n aggn[b,n,c,j].  total = BS*VD*HW = 131072
__global__ __launch_bounds__(256) void k_aggred(
    const float* __restrict__ aggn, float* __restrict__ f16) {
  int idx = blockIdx.x * 256 + threadIdx.x;
  int j = idx & 255;
  int c = (idx >> 8) & 127;
  int b = idx >> 15;
  float s = 0.f;
#pragma unroll
  for (int n = 0; n < NCLS; ++n)
    s += aggn[(((size_t)b * NCLS + n) * VD + c) * HW + j];
  f16[((size_t)b * CIN + VD + c) * HW + j] = s;
}

// ---------------------------------------------------------------------------
// g16_all[l,b,oc,j] = sum_c cw[oc,256+c]*(gamma[l,c]*BNC)*f16_all[l,b,c,j]
// grid = 5*4*32 (8 oc per block)
__global__ __launch_bounds__(256) void k_g16_all(
    const float* __restrict__ f16_all, const float* __restrict__ cw,
    const float* __restrict__ gamma, float* __restrict__ g16_all) {
  int blk = blockIdx.x;
  int l = blk >> 7, b = (blk >> 5) & 3, ocg = blk & 31;
  int j = threadIdx.x;
  const float* f16 = f16_all + (size_t)(l * 4 + b) * CIN * HW;
  const float* gm  = gamma + l * CIN;
  float acc[8] = {};
  for (int c = 0; c < CIN; ++c) {
    float fv = f16[(size_t)c * HW + j] * (gm[c] * BNC);
#pragma unroll
    for (int o = 0; o < 8; ++o)
      acc[o] += cw[(size_t)(ocg * 8 + o) * 512 + 256 + c] * fv;
  }
  for (int o = 0; o < 8; ++o)
    g16_all[((size_t)(l * 4 + b) * CIN + ocg * 8 + o) * HW + j] = acc[o];
}

// cb[l,oc] = combine_b[oc] + sum_c cw[oc,256+c]*beta[l,c].  grid=5, block=256
__global__ __launch_bounds__(256) void k_cb(
    const float* __restrict__ cw, const float* __restrict__ cbias,
    const float* __restrict__ beta, float* __restrict__ cb) {
  int l = blockIdx.x, oc = threadIdx.x;
  float s = cbias[oc];
  for (int c = 0; c < CIN; ++c)
    s += cw[(size_t)oc * 512 + 256 + c] * beta[l * CIN + c];
  cb[l * CIN + oc] = s;
}

// ---------------------------------------------------------------------------
// Merged final conv across all 5 levels. Per-level block counts:
// chunks={16,4,1,1,1} -> blocks = 32*chunks = {512,128,32,32,32}, cum below.
__global__ __launch_bounds__(256) void k_out_all(
    const float* __restrict__ f0, const float* __restrict__ f1,
    const float* __restrict__ f2, const float* __restrict__ f3,
    const float* __restrict__ f4, const float* __restrict__ cw,
    const float* __restrict__ g16_all, const float* __restrict__ cb_all,
    float* __restrict__ out) {
  constexpr int cum[5]    = {512, 640, 672, 704, 736};
  constexpr int chn[5]    = {16, 4, 1, 1, 1};
  constexpr int shf[5]    = {6, 5, 4, 3, 2};
  constexpr size_t ooff[5] = {0, 4194304, 5242880, 5505024, 5570560};
  int blk = blockIdx.x;
  int l = 0;
#pragma unroll
  for (int q = 0; q < 4; ++q) if (blk >= cum[q]) l = q + 1;
  int base = (l == 0) ? 0 : cum[l - 1];
  int local = blk - base;
  int chunks = chn[l], shift = shf[l];
  int S = 64 >> l, SS = S * S;
  int ch = local % chunks;
  int t  = local / chunks;
  int ocg = t & 7, b = t >> 3;
  int pix = ch * 256 + threadIdx.x;
  if (pix >= SS) return;
  const float* f;
  switch (l) {
    case 0: f = f0; break; case 1: f = f1; break; case 2: f = f2; break;
    case 3: f = f3; break; default: f = f4; break;
  }
  int X = pix & (S - 1), Y = pix >> shift;
  float acc[32] = {};
  const float* fb = f + (size_t)b * CIN * SS + pix;
  for (int c = 0; c < CIN; ++c) {
    float fv = fb[(size_t)c * SS];
#pragma unroll
    for (int o = 0; o < 32; ++o)
      acc[o] += cw[(size_t)(ocg * 32 + o) * 512 + c] * fv;
  }
  float cyf = (float)(Y * 15) / (float)(S - 1);
  int ylo = imin((int)cyf, 14); float fy = cyf - (float)ylo;
  float cxf = (float)(X * 15) / (float)(S - 1);
  int xlo = imin((int)cxf, 14); float fx = cxf - (float)xlo;
  const float* gb = g16_all + ((size_t)(l * 4 + b) * CIN + ocg * 32) * HW + ylo * 16 + xlo;
  const float* cb = cb_all + l * CIN;
#pragma unroll
  for (int o = 0; o < 32; ++o) {
    const float* g = gb + (size_t)o * HW;
    float v0 = g[0], v1 = g[1], v2 = g[16], v3 = g[17];
    float bil = (1.f - fy) * ((1.f - fx) * v0 + fx * v1)
              + fy * ((1.f - fx) * v2 + fx * v3);
    out[ooff[l] + ((size_t)b * CIN + ocg * 32 + o) * SS + pix] = acc[o] + bil + cb[ocg * 32 + o];
  }
}

// ===========================================================================
extern "C" void kernel_launch(void* const* d_in, const int* in_sizes, int n_in,
                              void* d_out, int out_size, void* d_ws, size_t ws_size,
                              hipStream_t stream) {
  const float* feat[5];
  for (int l = 0; l < 5; ++l) feat[l] = (const float*)d_in[l];
  const float* att   = (const float*)d_in[5];
  const float* ktw   = (const float*)d_in[6];
  const float* ktb   = (const float*)d_in[7];
  const float* vtw   = (const float*)d_in[8];
  const float* vtb   = (const float*)d_in[9];
  const float* kqw   = (const float*)d_in[10];
  const float* kqb   = (const float*)d_in[11];
  const float* vqw   = (const float*)d_in[12];
  const float* vqb   = (const float*)d_in[13];
  const float* gamma = (const float*)d_in[14];
  const float* beta  = (const float*)d_in[15];
  const float* cw    = (const float*)d_in[16];
  const float* cbias = (const float*)d_in[17];
  float* out = (float*)d_out;

  // workspace layout (floats), total 7,128,320 fl = 28.5 MB
  float* ws      = (float*)d_ws;
  float* kqall   = ws;                    // [30][32][256]  = 245760 (20 lvl + 10 tmpl kt)
  float* vt      = kqall  + 245760;       // [10][128][256] = 327680
  float* f16_all = vt     + 327680;       // [20][256][256] = 1310720
  float* tail    = f16_all + 1310720;     // 5,244,160 fl region, time-shared:
  // conv phase:  X   = (u16*)tail            (30*18*18*512   = 4,976,640 u16)
  //              Awv = (u16*)(tail+2488320)  (6*8*72*1024    = 3,538,944 u16)
  //              Awk = (u16*)(tail+4257792)  (6*2*72*1024    =   884,736 u16)
  // later phase: g16_all = tail (1310720) | cb +1310720 (1280) | p +1312000
  //              (2621440) | aggn +3933440 (1310720)
  u16*   X       = (u16*)tail;
  u16*   Awv     = (u16*)(tail + 2488320);
  u16*   Awk     = (u16*)(tail + 4257792);
  float* g16_all = tail;
  float* cb      = tail + 1310720;
  float* p       = cb + 1280;
  float* aggn    = p + 2621440;

  size_t fa_off[5];
  {
    size_t off = 5586944;  // total outs
    static const int szs[5] = {64, 32, 16, 8, 4};
    for (int l = 0; l < 5; ++l) { fa_off[l] = off; off += (size_t)BS * NCLS * HW * szs[l] * szs[l]; }
  }
  static const int sizes[5]  = {64, 32, 16, 8, 4};
  static const int shifts[5] = {6, 5, 4, 3, 2};

  // Stage 1: prep (fused resize) + MFMA convs
  k_prep_x<<<540, 256, 0, stream>>>(
      feat[0], feat[1], feat[2], feat[3], feat[4], att, X);
  k_prep_w<<<1080, 256, 0, stream>>>(vqw, vtw, kqw, ktw, Awv, Awk);
  k_conv_mfma<<<600, 256, 0, stream>>>(
      X, Awv, Awk, kqall, vt, f16_all, vqb, vtb, kqb, ktb);
  k_cb<<<5, 256, 0, stream>>>(cw, cbias, beta, cb);   // after convs (cb aliases X)

  // Stage 2: per-level p-chain (p buffer reused; overwrites X/Aw region)
  for (int l = 0; l < 5; ++l) {
    k_p_fused<<<40 * 8, 256, 0, stream>>>(
        kqall + (size_t)l * 4 * KD * HW, kqall + 20 * KD * HW, p);
    k_fa_t<<<40 * 16, 256, 0, stream>>>(p, out + fa_off[l], sizes[l], shifts[l]);
    k_aggn<<<40 * 16, 256, 0, stream>>>(vt, p, aggn);
    k_aggred<<<BS * VD * HW / 256, 256, 0, stream>>>(
        aggn, f16_all + (size_t)l * 4 * CIN * HW);
  }

  // Stage 3: combine (merged across levels)
  k_g16_all<<<5 * 4 * 32, 256, 0, stream>>>(f16_all, cw, gamma, g16_all);
  k_out_all<<<736, 256, 0, stream>>>(
      feat[0], feat[1], feat[2], feat[3], feat[4], cw, g16_all, cb, out);
}